// Round 1
// baseline (62.939 us; speedup 1.0000x reference)
//
#include <hip/hip_runtime.h>
#include <math.h>

// ANFIS model, collapsed analytically:
//   All MEM_INDEX rows use the same leading base-3 digit d = r // 2187, and
//   w[j,b] == F0[b]/S for all j (J_LAST=2 -> digit 0). Hence
//     out[b] = F0[b]/S * ( sum_v input[v,b]*Sv[v] + Sv[8] )
//   with Sv[v] = sum_j conseq[9j+v], S = 2187 * sum_b (F0+F1+F2)[b],
//   F_d[b] = prod_{i=0..7} 1/(1 + (((x_i-c)/a)^2)^bexp) over rows k=3i+d.

#define NVAR 8
#define TOTALJ 6561
#define NB 2048
#define K1_BLOCKS 64
#define K1_THREADS 256
#define K2_BLOCKS 8
#define K2_THREADS 256

// ws layout (floats):
//   [0,   576)  SvPart[block][9]
//   [576, 640)  SsumPart[block]
//   [640, 2688) F0[b]
#define WS_SV    0
#define WS_SSUM  576
#define WS_F0    640

__global__ __launch_bounds__(K1_THREADS) void anfis_k1(
    const float* __restrict__ input,     // (8, 2048)
    const float* __restrict__ premise,   // (24, 3) rows [a, b, c]
    const float* __restrict__ conseq,    // (59049,)
    float* __restrict__ ws)
{
    const int t    = threadIdx.x;
    const int g    = blockIdx.x;
    const int gt   = g * K1_THREADS + t;
    const int wave = t >> 6;
    const int lane = t & 63;

    // ---- Part A: Sv partial sums (one conseq row of 9 per thread) ----
    float sv[9];
    #pragma unroll
    for (int v = 0; v < 9; ++v) sv[v] = 0.0f;
    if (gt < TOTALJ) {
        const float* row = conseq + gt * 9;
        #pragma unroll
        for (int v = 0; v < 9; ++v) sv[v] = row[v];
    }
    #pragma unroll
    for (int v = 0; v < 9; ++v) {
        #pragma unroll
        for (int m = 32; m; m >>= 1) sv[v] += __shfl_xor(sv[v], m);
    }
    __shared__ float s_sv[4][9];
    if (lane == 0) {
        #pragma unroll
        for (int v = 0; v < 9; ++v) s_sv[wave][v] = sv[v];
    }

    // ---- Part B: membership + F0 per batch (8 lanes per batch) ----
    const int i  = t & 7;          // variable index 0..7
    const int bl = t >> 3;         // local batch 0..31
    const int b  = g * 32 + bl;

    const float x = input[i * NB + b];
    float m3[3];
    #pragma unroll
    for (int d = 0; d < 3; ++d) {
        const int k = 3 * i + d;
        const float pa = premise[k * 3 + 0];
        const float pb = premise[k * 3 + 1];
        const float pc = premise[k * 3 + 2];
        const float tt = (x - pc) / pa;
        const float x2 = tt * tt;
        m3[d] = 1.0f / (1.0f + powf(x2, pb));
    }
    // product across the 8 lanes of this batch's group (groups are lane-aligned)
    #pragma unroll
    for (int d = 0; d < 3; ++d) {
        m3[d] *= __shfl_xor(m3[d], 1);
        m3[d] *= __shfl_xor(m3[d], 2);
        m3[d] *= __shfl_xor(m3[d], 4);
    }
    if (i == 0) ws[WS_F0 + b] = m3[0];

    float contrib = (i == 0) ? (m3[0] + m3[1] + m3[2]) : 0.0f;
    #pragma unroll
    for (int m = 32; m; m >>= 1) contrib += __shfl_xor(contrib, m);
    __shared__ float s_c[4];
    if (lane == 0) s_c[wave] = contrib;

    __syncthreads();
    if (t < 9) {
        ws[WS_SV + g * 9 + t] = s_sv[0][t] + s_sv[1][t] + s_sv[2][t] + s_sv[3][t];
    }
    if (t == 9) {
        ws[WS_SSUM + g] = s_c[0] + s_c[1] + s_c[2] + s_c[3];
    }
}

__global__ __launch_bounds__(K2_THREADS) void anfis_k2(
    const float* __restrict__ input,
    const float* __restrict__ ws,
    float* __restrict__ out)
{
    __shared__ float s_Sv[9];
    __shared__ float s_invS;
    const int t = threadIdx.x;

    if (t < 9) {
        float s = 0.0f;
        #pragma unroll 8
        for (int g = 0; g < K1_BLOCKS; ++g) s += ws[WS_SV + g * 9 + t];
        s_Sv[t] = s;
    }
    if (t >= 64 && t < 128) {
        float s = ws[WS_SSUM + (t - 64)];
        #pragma unroll
        for (int m = 32; m; m >>= 1) s += __shfl_xor(s, m);
        if (t == 64) s_invS = 1.0f / (2187.0f * s);
    }
    __syncthreads();

    const int b = blockIdx.x * K2_THREADS + t;
    float D = s_Sv[8];
    #pragma unroll
    for (int v = 0; v < 8; ++v) D += input[v * NB + b] * s_Sv[v];
    out[b] = ws[WS_F0 + b] * D * s_invS;
}

extern "C" void kernel_launch(void* const* d_in, const int* in_sizes, int n_in,
                              void* d_out, int out_size, void* d_ws, size_t ws_size,
                              hipStream_t stream) {
    const float* input   = (const float*)d_in[0];   // 8*2048
    const float* premise = (const float*)d_in[1];   // 24*3
    const float* conseq  = (const float*)d_in[2];   // 59049
    float* out = (float*)d_out;                     // 2048
    float* ws  = (float*)d_ws;

    anfis_k1<<<K1_BLOCKS, K1_THREADS, 0, stream>>>(input, premise, conseq, ws);
    anfis_k2<<<K2_BLOCKS, K2_THREADS, 0, stream>>>(input, ws, out);
}